// Round 1
// baseline (3550.077 us; speedup 1.0000x reference)
//
#include <hip/hip_runtime.h>

// IPLayer: out[a, g] = sum over pairs p with ind_2[p,0]==a of inter[p, g]
// N_ATOMS=100000, N_PAIRS=3200000, N_INTER=64. prop (d_in[1]) is unused.

#define N_ATOMS_C 100000
#define N_PAIRS_C 3200000
#define N_INTER_C 64

// One thread per (pair, 4-gamma chunk): 16 threads per pair.
// float4 coalesced load from inter, 4 dword atomicAdds into out.
__global__ __launch_bounds__(256) void ip_scatter_kernel(
    const int* __restrict__ ind2,
    const float* __restrict__ inter,
    float* __restrict__ out)
{
    long long t = (long long)blockIdx.x * blockDim.x + threadIdx.x;
    int pair = (int)(t >> 4);
    if (pair >= N_PAIRS_C) return;
    int c = ((int)t & 15) << 2;  // gamma offset: 0,4,...,60

    int a = ind2[2 * pair];  // first atom index of the pair (broadcast across 16 lanes)

    const float4 v = *reinterpret_cast<const float4*>(
        inter + (long long)pair * N_INTER_C + c);

    float* o = out + (long long)a * N_INTER_C + c;
    atomicAdd(o + 0, v.x);
    atomicAdd(o + 1, v.y);
    atomicAdd(o + 2, v.z);
    atomicAdd(o + 3, v.w);
}

extern "C" void kernel_launch(void* const* d_in, const int* in_sizes, int n_in,
                              void* d_out, int out_size, void* d_ws, size_t ws_size,
                              hipStream_t stream) {
    const int*   ind2  = (const int*)d_in[0];   // (N_PAIRS, 2) int32
    const float* inter = (const float*)d_in[2]; // (N_PAIRS, 64) f32
    float*       out   = (float*)d_out;         // (N_ATOMS, 64) f32

    // d_out is poisoned to 0xAA before every timed launch — zero it first.
    hipMemsetAsync(d_out, 0, (size_t)out_size * sizeof(float), stream);

    const long long total_threads = (long long)N_PAIRS_C * 16;
    const int block = 256;
    const long long grid = (total_threads + block - 1) / block;  // 200000 blocks

    ip_scatter_kernel<<<(int)grid, block, 0, stream>>>(ind2, inter, out);
}

// Round 2
// 1671.144 us; speedup vs baseline: 2.1243x; 2.1243x over previous
//
#include <hip/hip_runtime.h>

// IPLayer: out[a, g] = sum over pairs p with ind_2[p,0]==a of inter[p, g]
// Strategy: CSR build (count/scan/fill) + per-wave gather. No fp32 atomics.

#define NA 100000
#define NP 3200000
#define NG 64

// ws layout (int32): counts/rowptr [NA+1] | cursor [NA] | csr [NP]  (~13.6 MB)

__global__ __launch_bounds__(256) void count_kernel(const int* __restrict__ ind2,
                                                    int* __restrict__ counts) {
    int p = blockIdx.x * 256 + threadIdx.x;
    if (p < NP) atomicAdd(&counts[ind2[2 * p]], 1);
}

__global__ __launch_bounds__(1024) void scan_kernel(int* __restrict__ counts,
                                                    int* __restrict__ cursor) {
    // Exclusive scan of counts[0..NA) in place -> rowptr; also copy to cursor.
    __shared__ int sums[1024];
    const int T = 1024;
    const int chunk = (NA + T - 1) / T;  // 98
    int t = threadIdx.x;
    int beg = t * chunk;
    int end = min(beg + chunk, NA);
    int s = 0;
    for (int i = beg; i < end; ++i) s += counts[i];
    sums[t] = s;
    __syncthreads();
    // Hillis-Steele inclusive scan over the 1024 chunk sums
    for (int off = 1; off < T; off <<= 1) {
        int v = (t >= off) ? sums[t - off] : 0;
        __syncthreads();
        sums[t] += v;
        __syncthreads();
    }
    int run = (t == 0) ? 0 : sums[t - 1];  // exclusive base of this chunk
    for (int i = beg; i < end; ++i) {
        int c = counts[i];
        counts[i] = run;
        cursor[i] = run;
        run += c;
    }
    if (t == T - 1) counts[NA] = NP;
}

__global__ __launch_bounds__(256) void fill_kernel(const int* __restrict__ ind2,
                                                   int* __restrict__ cursor,
                                                   int* __restrict__ csr) {
    int p = blockIdx.x * 256 + threadIdx.x;
    if (p < NP) {
        int a = ind2[2 * p];
        int pos = atomicAdd(&cursor[a], 1);
        csr[pos] = p;
    }
}

// One wave per atom; lane = gamma. 4 atoms per 256-thread block.
__global__ __launch_bounds__(256) void gather_kernel(const int* __restrict__ rowptr,
                                                     const int* __restrict__ csr,
                                                     const float* __restrict__ inter,
                                                     float* __restrict__ out) {
    int wave = threadIdx.x >> 6;
    int lane = threadIdx.x & 63;
    int a = blockIdx.x * 4 + wave;
    if (a >= NA) return;

    int beg = rowptr[a];
    int end = rowptr[a + 1];
    float acc = 0.f;

    for (int base = beg; base < end; base += 64) {
        int n = min(64, end - base);
        int myid = (lane < n) ? csr[base + lane] : 0;  // coalesced pair-id load
        int j = 0;
        for (; j + 4 <= n; j += 4) {  // 4 independent row loads in flight
            int p0 = __shfl(myid, j + 0);
            int p1 = __shfl(myid, j + 1);
            int p2 = __shfl(myid, j + 2);
            int p3 = __shfl(myid, j + 3);
            float v0 = inter[(long long)p0 * NG + lane];
            float v1 = inter[(long long)p1 * NG + lane];
            float v2 = inter[(long long)p2 * NG + lane];
            float v3 = inter[(long long)p3 * NG + lane];
            acc += v0 + v1 + v2 + v3;
        }
        for (; j < n; ++j) {
            int p = __shfl(myid, j);
            acc += inter[(long long)p * NG + lane];
        }
    }
    out[(long long)a * NG + lane] = acc;  // single non-atomic write per element
}

extern "C" void kernel_launch(void* const* d_in, const int* in_sizes, int n_in,
                              void* d_out, int out_size, void* d_ws, size_t ws_size,
                              hipStream_t stream) {
    const int*   ind2  = (const int*)d_in[0];   // (NP, 2) int32
    const float* inter = (const float*)d_in[2]; // (NP, 64) f32
    float*       out   = (float*)d_out;         // (NA, 64) f32

    int* counts = (int*)d_ws;            // NA+1 (becomes rowptr)
    int* cursor = counts + (NA + 1);     // NA
    int* csr    = cursor + NA;           // NP

    // counts must start at zero (ws is poisoned to 0xAA each run)
    hipMemsetAsync(counts, 0, (size_t)(NA + 1) * sizeof(int), stream);

    count_kernel<<<(NP + 255) / 256, 256, 0, stream>>>(ind2, counts);
    scan_kernel<<<1, 1024, 0, stream>>>(counts, cursor);
    fill_kernel<<<(NP + 255) / 256, 256, 0, stream>>>(ind2, cursor, csr);
    gather_kernel<<<(NA + 3) / 4, 256, 0, stream>>>(counts, csr, inter, out);
    // gather writes every output element -> no d_out memset needed
}